// Round 13
// baseline (147.656 us; speedup 1.0000x reference)
//
#include <hip/hip_runtime.h>
#include <hip/hip_bf16.h>

// ---------------------------------------------------------------------------
// EuclideanDeconf: out[b,c] = (2*dot(x[b],W[c]) - ||x[b]||^2 - ||W[c]||^2) / D
// R19: the untested cell of the {staging}x{TLP} matrix. Campaign so far:
// LDS+barriers @1 or 3 waves/SIMD = 30-35us (barriers defeat TLP); no-LDS
// @1 wave/SIMD = 34-43us (lone wave's WAITV idles the SIMD). R15 profile:
// MfmaUtil 14%, VALU 7%, HBM 12% -> latency-bound. R19 = no-LDS frag-major
// register loads (R16, HW-verified) + ZERO barriers + KSPLIT=4 -> grid
// (32,8,4)=1024 blocks, __launch_bounds__(256,3) -> 3 independent waves/SIMD:
// when a wave waits, the SIMD runs another wave's MFMAs (TLP, applicable for
// the first time). Ring-2 frag buffers, counted WAITV(8) (drains only in the
// peeled last iter). Partials/reduce verbatim from R12 (HW-passed, same
// geometry). 128x128 block, 4 waves 2x2 (64x64/wave), fp8 partials (1/16).
// ---------------------------------------------------------------------------

typedef float f32x4 __attribute__((ext_vector_type(4)));
typedef float f32x2 __attribute__((ext_vector_type(2)));
typedef float f32x16 __attribute__((ext_vector_type(16)));
typedef int i32x4 __attribute__((ext_vector_type(4)));
typedef int i32x8 __attribute__((ext_vector_type(8)));

#define BDIM 4096
#define DDIM 4096
#define CDIM 1024
#define TM 128
#define TN 128
#define KSPLIT 4
#define NIT 16                        // k-tiles (K=64 each) per z-slice
#define SCALE 32.0f
#define INV_SS (1.0f/1024.0f)
#define PSCALE 0.0625f                // partial pack scale (1/16)

#define WAITV(N) asm volatile("s_waitcnt vmcnt(" #N ")" ::: "memory")

// One WAVE per row: fp32 row -> fp8(e4m3, x SCALE) in FRAGMENT-MAJOR layout
// + fp32 sum-of-squares of the UNSCALED values. (R16/R17, HW-verified.)
// Fragment tile (mt=row>>5, kt): 2048B at (mt*64+kt)*2048; element (row,k)
// at lane*32 + (k&31) with lane = (row&31) + 32*((k>>5)&1).
// Lane l covers k-floats [l*64, l*64+64) = k-tile kt=l of this row.
__global__ __launch_bounds__(256) void cvt_rowsq(
    const float* __restrict__ x, const float* __restrict__ W,
    unsigned char* __restrict__ xb, unsigned char* __restrict__ wb,
    float* __restrict__ xsq, float* __restrict__ wsq)
{
    const int lane = threadIdx.x & 63;
    const int row = blockIdx.x * 4 + (threadIdx.x >> 6);

    const float* src;
    unsigned char* dstb;
    float* sq;
    int r;
    if (row < BDIM) {
        src = x + (size_t)row * DDIM;
        dstb = xb; r = row;
        sq = xsq + row;
    } else {
        r = row - BDIM;
        src = W + (size_t)r * DDIM;
        dstb = wb;
        sq = wsq + r;
    }

    const float4* s4 = (const float4*)src;
    float a = 0.f;
    unsigned int pk[16];
    #pragma unroll
    for (int u = 0; u < 16; ++u) {
        float4 f = s4[lane * 16 + u];
        a += f.x * f.x + f.y * f.y + f.z * f.z + f.w * f.w;
        unsigned int p = 0;
        p = __builtin_amdgcn_cvt_pk_fp8_f32(f.x * SCALE, f.y * SCALE, p, false);
        p = __builtin_amdgcn_cvt_pk_fp8_f32(f.z * SCALE, f.w * SCALE, p, true);
        pk[u] = p;
    }
    unsigned char* db = dstb + (size_t)(r >> 5) * 131072
                      + (size_t)lane * 2048 + (r & 31) * 32;
    i32x4 v0 = {(int)pk[0], (int)pk[1], (int)pk[2], (int)pk[3]};
    i32x4 v1 = {(int)pk[4], (int)pk[5], (int)pk[6], (int)pk[7]};
    i32x4 v2 = {(int)pk[8], (int)pk[9], (int)pk[10], (int)pk[11]};
    i32x4 v3 = {(int)pk[12], (int)pk[13], (int)pk[14], (int)pk[15]};
    *(i32x4*)(db)        = v0;
    *(i32x4*)(db + 16)   = v1;
    *(i32x4*)(db + 1024) = v2;
    *(i32x4*)(db + 1040) = v3;

    #pragma unroll
    for (int off = 32; off > 0; off >>= 1) a += __shfl_down(a, off);
    if (lane == 0) *sq = a;
}

// --- GEMM: no LDS, no barriers, TLP via 3 waves/SIMD ---
__device__ __forceinline__ i32x8 ld8(const unsigned char* p) {
    return *(const i32x8*)p;
}

#define MXMFMA(A, Bv, C)                                                  \
    __builtin_amdgcn_mfma_scale_f32_32x32x64_f8f6f4(                      \
        (A), (Bv), (C), 0, 0, 0, 0x7F7F7F7F, 0, 0x7F7F7F7F)

struct FragT { i32x8 a0, a1, b0, b1; };   // one K-tile of operands (32 VGPR)

__global__ __launch_bounds__(256, 3) void gemm_eucl(
    const unsigned char* __restrict__ xb,   // [B/32][64][64][32] fp8 frag-major
    const unsigned char* __restrict__ wb,   // [C/32][64][64][32] fp8 frag-major
    unsigned int* __restrict__ part)        // [KSPLIT][256 blk][16 fg][256]
{
    const int tid = threadIdx.x;
    const int lane = tid & 63;
    const int w = tid >> 6;                 // wave 0..3
    const int wr = w >> 1;                  // 0..1  (M half: 64 rows)
    const int wc = w & 1;                   // 0..1  (N half: 64 rows)

    // wave's frag-tile origins; K-slice base folded into the pointers
    const int mt0 = blockIdx.x * 4 + wr * 2;
    const int nt0 = blockIdx.y * 4 + wc * 2;
    const size_t kof = (size_t)blockIdx.z * NIT * 2048;
    const unsigned char* pA0 = xb + (size_t)(mt0 + 0) * 131072 + kof + (size_t)lane * 32;
    const unsigned char* pA1 = xb + (size_t)(mt0 + 1) * 131072 + kof + (size_t)lane * 32;
    const unsigned char* pB0 = wb + (size_t)(nt0 + 0) * 131072 + kof + (size_t)lane * 32;
    const unsigned char* pB1 = wb + (size_t)(nt0 + 1) * 131072 + kof + (size_t)lane * 32;

#define LOADF(S, t)                                                       \
    do {                                                                  \
        (S).a0 = ld8(pA0 + (size_t)(t) * 2048);                           \
        (S).a1 = ld8(pA1 + (size_t)(t) * 2048);                           \
        (S).b0 = ld8(pB0 + (size_t)(t) * 2048);                           \
        (S).b1 = ld8(pB1 + (size_t)(t) * 2048);                           \
    } while (0)

    f32x16 acc[4] = {};   // [i 0..1][j 0..1] -> acc[i*2+j]

#define COMPUTE(S)                                                       \
    do {                                                                 \
        __builtin_amdgcn_s_setprio(1);                                   \
        acc[0] = MXMFMA((S).a0, (S).b0, acc[0]);                         \
        acc[1] = MXMFMA((S).a0, (S).b1, acc[1]);                         \
        acc[2] = MXMFMA((S).a1, (S).b0, acc[2]);                         \
        acc[3] = MXMFMA((S).a1, (S).b1, acc[3]);                         \
        __builtin_amdgcn_s_setprio(0);                                   \
    } while (0)

    FragT S[2];
    // prologue: tiles 0,1 in flight (16 dwordx4)
    LOADF(S[0], 0);
    LOADF(S[1], 1);

    // barrier-free main loop: WAITV(8) retires tile t's 8 loads (FIFO, this
    // wave's own); tile t+1's 8 stay flying; refill slot with tile t+2.
    #pragma unroll
    for (int t = 0; t < NIT - 2; ++t) {
        WAITV(8);
        COMPUTE(S[t & 1]);
        LOADF(S[t & 1], t + 2);
    }
    WAITV(8); COMPUTE(S[(NIT - 2) & 1]);   // t=14
    WAITV(0); COMPUTE(S[(NIT - 1) & 1]);   // t=15

    // ---- fp8 partials, scale 1/16: 16 uints/thread (R12, HW-verified) ----
    const int bb = blockIdx.x * 8 + blockIdx.y;          // 0..255
    unsigned int* p = part + ((size_t)blockIdx.z * 256 + bb) * 4096;
    #pragma unroll
    for (int f = 0; f < 4; ++f)
        #pragma unroll
        for (int g = 0; g < 4; ++g) {
            unsigned int pk = 0;
            pk = __builtin_amdgcn_cvt_pk_fp8_f32(
                acc[f][g * 4 + 0] * PSCALE, acc[f][g * 4 + 1] * PSCALE, pk, false);
            pk = __builtin_amdgcn_cvt_pk_fp8_f32(
                acc[f][g * 4 + 2] * PSCALE, acc[f][g * 4 + 3] * PSCALE, pk, true);
            p[(f * 4 + g) * 256 + tid] = pk;
        }
#undef LOADF
#undef COMPUTE
}

// 512 blocks x 256 thr; reduce block = half of one gemm-block (8 fg's).
// (R12, HW-verified.) 32x32 C/D layout: col = lane&31,
// row = (reg&3)+8*(reg>>2)+4*(lane>>5); grp g: row = r + 8g + 4*(lane>>5).
__global__ __launch_bounds__(256) void reduce_out(
    const unsigned int* __restrict__ part, const float* __restrict__ xsq,
    const float* __restrict__ wsq, float* __restrict__ out)
{
    const int bid = blockIdx.x;           // 0..511
    const int bb = bid >> 1;              // gemm block 0..255 (bx*8 + by)
    const int half = bid & 1;
    const int t = threadIdx.x;
    const int lane = t & 63;
    const int w = t >> 6;                 // gemm wave 0..3
    const int wr = w >> 1, wc = w & 1;
    const int bm = (bb >> 3) * TM, bn = (bb & 7) * TN;
    const size_t sl = (size_t)256 * 4096;        // uints per z-slice
    const float c1 = 2.0f * 16.0f * INV_SS / (float)DDIM;  // 16 = 1/PSCALE
    const float c2 = 1.0f / (float)DDIM;

    #pragma unroll
    for (int ff = 0; ff < 8; ++ff) {
        const int fg = half * 8 + ff;     // 0..15
        const int f = fg >> 2;            // acc index 0..3
        const int g = fg & 3;             // packed group
        size_t o = ((size_t)bb * 16 + fg) * 256 + t;
        f32x2 s01 = {0.f, 0.f}, s23 = {0.f, 0.f};
        #pragma unroll
        for (int z = 0; z < KSPLIT; ++z) {
            unsigned int u = part[o + (size_t)z * sl];
            s01 += __builtin_amdgcn_cvt_pk_f32_fp8(u, false);
            s23 += __builtin_amdgcn_cvt_pk_f32_fp8(u, true);
        }
        const int i = f >> 1, j = f & 1;
        const int gn = bn + wc * 64 + j * 32 + (lane & 31);
        const float wv = wsq[gn];
        const int gm0 = bm + wr * 64 + i * 32 + g * 8 + (lane >> 5) * 4;
        float sv[4] = {s01.x, s01.y, s23.x, s23.y};
        #pragma unroll
        for (int r = 0; r < 4; ++r) {
            out[(size_t)(gm0 + r) * CDIM + gn] = sv[r] * c1 - (xsq[gm0 + r] + wv) * c2;
        }
    }
}

// --- Fallback: naive fp32 (any ws) ---
__global__ void fallback_kernel(const float* __restrict__ x, const float* __restrict__ W,
                                float* __restrict__ out)
{
    int c = blockIdx.x * blockDim.x + threadIdx.x;
    int b = blockIdx.y;
    if (c >= CDIM) return;
    const float* xr = x + (size_t)b * DDIM;
    const float* wr = W + (size_t)c * DDIM;
    float xs = 0.f, ws = 0.f, cr = 0.f;
    for (int d = 0; d < DDIM; ++d) {
        float xv = xr[d], wv = wr[d];
        xs += xv * xv; ws += wv * wv; cr += xv * wv;
    }
    out[(size_t)b * CDIM + c] = (2.0f * cr - xs - ws) / (float)DDIM;
}

extern "C" void kernel_launch(void* const* d_in, const int* in_sizes, int n_in,
                              void* d_out, int out_size, void* d_ws, size_t ws_size,
                              hipStream_t stream) {
    const float* x = (const float*)d_in[0];   // [B, D] fp32
    const float* W = (const float*)d_in[1];   // [C, D] fp32
    float* out = (float*)d_out;               // [B, C] fp32

    size_t need = (size_t)(BDIM + CDIM) * DDIM                 // fp8 inputs 20 MB
                + (size_t)(BDIM + CDIM) * sizeof(float)        // norms
                + (size_t)KSPLIT * BDIM * CDIM;                // fp8 partials 16 MB
    if (ws_size < need) {
        fallback_kernel<<<dim3(CDIM / 256, BDIM), 256, 0, stream>>>(x, W, out);
        return;
    }

    unsigned char* xb = (unsigned char*)d_ws;              // 16 MB (frag-major)
    unsigned char* wb = xb + (size_t)BDIM * DDIM;          // 4 MB (frag-major)
    float* xsq = (float*)(wb + (size_t)CDIM * DDIM);       // 16 KB
    float* wsq = xsq + BDIM;                               // 4 KB
    unsigned int* part = (unsigned int*)(wsq + CDIM);      // 16 MB

    cvt_rowsq<<<(BDIM + CDIM) / 4, 256, 0, stream>>>(x, W, xb, wb, xsq, wsq);
    gemm_eucl<<<dim3(BDIM / TM, CDIM / TN, KSPLIT), 256, 0, stream>>>(xb, wb, part);
    reduce_out<<<512, 256, 0, stream>>>(part, xsq, wsq, out);
}

// Round 14
// 132.386 us; speedup vs baseline: 1.1153x; 1.1153x over previous
//
#include <hip/hip_runtime.h>
#include <hip/hip_bf16.h>

// ---------------------------------------------------------------------------
// EuclideanDeconf: out[b,c] = (2*dot(x[b],W[c]) - ||x[b]||^2 - ||W[c]||^2) / D
// R20 = R14 restored verbatim (session best, HW-verified 132.6us).
// Campaign conclusion (R8-R19, 12 structures): gemm pinned at 30-43us across
// {LDS/reg/no staging} x {0-8 barriers/tile} x {1-3 blocks/CU} x {0.5-2
// MFMA/load} x {BK 64/128}; only arithmetic/traffic changes paid (MX MFMA
// +4.8us, split-K deletion + fused epilogue +2.1us). Remaining headroom is
// hand-asm-class scheduling, not expressible at HIP source for this shape.
// Structure: KSPLIT=1, NIT=64, ring-of-4 LDS bufs (64 KB), PD=2-tile flight,
// counted WAITV(4) (drains only in 2 peeled tail iters), pre-swizzled DMA
// source + swizzled conflict-free b128 reads (rule #21), MX-scaled MFMA
// 32x32x64 (unit E8M0 = exact fp8 math), epilogue fused into the gemm.
// 128x128xBK64, 256 thr (4 waves 2x2, wave=64x64), grid (32,8)=256.
// ---------------------------------------------------------------------------

typedef float f32x4 __attribute__((ext_vector_type(4)));
typedef float f32x2 __attribute__((ext_vector_type(2)));
typedef float f32x16 __attribute__((ext_vector_type(16)));
typedef int i32x4 __attribute__((ext_vector_type(4)));
typedef int i32x8 __attribute__((ext_vector_type(8)));

#define BDIM 4096
#define DDIM 4096
#define CDIM 1024
#define TM 128
#define TN 128
#define BK 64
#define NIT (DDIM / BK)              // 64
#define SCALE 32.0f
#define INV_SS (1.0f/1024.0f)

#define WAITV(N) asm volatile("s_waitcnt vmcnt(" #N ")" ::: "memory")
#define BAR()    __builtin_amdgcn_s_barrier()

// One WAVE per row: fp32 row -> fp8(e4m3, x SCALE) row + fp32 sum-of-squares
// (of the UNSCALED values).
__global__ __launch_bounds__(256) void cvt_rowsq(
    const float* __restrict__ x, const float* __restrict__ W,
    unsigned char* __restrict__ xb, unsigned char* __restrict__ wb,
    float* __restrict__ xsq, float* __restrict__ wsq)
{
    const int lane = threadIdx.x & 63;
    const int row = blockIdx.x * 4 + (threadIdx.x >> 6);

    const float* src;
    unsigned char* dst;
    float* sq;
    if (row < BDIM) {
        src = x + (size_t)row * DDIM;
        dst = xb + (size_t)row * DDIM;
        sq = xsq + row;
    } else {
        int r = row - BDIM;
        src = W + (size_t)r * DDIM;
        dst = wb + (size_t)r * DDIM;
        sq = wsq + r;
    }

    const float4* s4 = (const float4*)src;
    unsigned int* d4 = (unsigned int*)dst;
    float a = 0.f;
    #pragma unroll
    for (int s = 0; s < DDIM / 4 / 64; ++s) {
        float4 f = s4[lane + 64 * s];
        a += f.x * f.x + f.y * f.y + f.z * f.z + f.w * f.w;
        unsigned int p = 0;
        p = __builtin_amdgcn_cvt_pk_fp8_f32(f.x * SCALE, f.y * SCALE, p, false);
        p = __builtin_amdgcn_cvt_pk_fp8_f32(f.z * SCALE, f.w * SCALE, p, true);
        d4[lane + 64 * s] = p;
    }
    #pragma unroll
    for (int off = 32; off > 0; off >>= 1) a += __shfl_down(a, off);
    if (lane == 0) *sq = a;
}

// --- GEMM + fused epilogue ---
// LDS: 4 bufs, buf q at q*16384: A[128][64] fp8 at +0, B[128][64] at +8192.
// Swizzle: 16B chunk (row m, chunk c) stored at slot (m, c ^ ((m>>1)&3)).
// Staging (verified R12): wave w rows w*32+(lane>>2) (+16 for 2nd inst),
// slot lane&3 holds global chunk (lane&3)^((lane>>3)&3); DMA writes linearly
// (base + lane*16); per-lane SOURCE pre-swizzled, same 64B line per 4-lane
// group -> fully coalesced.
// Frag reads (verified R12): lane l: row base+(l&31), chunks c0=(l>>5)*2 and
// c0^1 swizzled -> two ds_read_b128; 8-lane groups cover all 32 banks.

__device__ __forceinline__ i32x8 cat8(i32x4 lo, i32x4 hi) {
    return __builtin_shufflevector(lo, hi, 0, 1, 2, 3, 4, 5, 6, 7);
}

#define MXMFMA(A, Bv, C)                                                  \
    __builtin_amdgcn_mfma_scale_f32_32x32x64_f8f6f4(                      \
        (A), (Bv), (C), 0, 0, 0, 0x7F7F7F7F, 0, 0x7F7F7F7F)

#define GLOAD16(gp, lp)                                                   \
    __builtin_amdgcn_global_load_lds(                                     \
        (const __attribute__((address_space(1))) void*)(gp),              \
        (__attribute__((address_space(3))) void*)(lp), 16, 0, 0)

__global__ __launch_bounds__(256) void gemm_eucl(
    const unsigned char* __restrict__ xb,   // [B, D] fp8
    const unsigned char* __restrict__ wb,   // [C, D] fp8
    const float* __restrict__ xsq, const float* __restrict__ wsq,
    float* __restrict__ out)                // [B, C] fp32
{
    __shared__ unsigned char sm[4 * 16384];

    const int tid = threadIdx.x;
    const int lane = tid & 63;
    const int w = tid >> 6;                 // wave 0..3
    const int wr = w >> 1;                  // 0..1  (M half: 64 rows)
    const int wc = w & 1;                   // 0..1  (N half: 64 rows)
    const int bm = blockIdx.x * TM;
    const int bn = blockIdx.y * TN;

    // ---- staging: per-lane pre-swizzled global sources (coalesced) ----
    const int srow = w * 32 + (lane >> 2);
    const int schunk = ((lane & 3) ^ ((lane >> 3) & 3)) * 16;
    const unsigned char* gA0 = xb + (size_t)(bm + srow) * DDIM + schunk;
    const unsigned char* gA1 = gA0 + (size_t)16 * DDIM;
    const unsigned char* gB0 = wb + (size_t)(bn + srow) * DDIM + schunk;
    const unsigned char* gB1 = gB0 + (size_t)16 * DDIM;
    // wave-uniform LDS dests (DMA adds lane*16)
    unsigned char* lA0 = sm + w * 2048;
    unsigned char* lA1 = lA0 + 1024;
    unsigned char* lB0 = sm + 8192 + w * 2048;
    unsigned char* lB1 = lB0 + 1024;

#define STAGE(q, t)                                                       \
    do {                                                                  \
        GLOAD16(gA0 + (t) * BK, lA0 + (q) * 16384);                       \
        GLOAD16(gA1 + (t) * BK, lA1 + (q) * 16384);                       \
        GLOAD16(gB0 + (t) * BK, lB0 + (q) * 16384);                       \
        GLOAD16(gB1 + (t) * BK, lB1 + (q) * 16384);                       \
    } while (0)

    // ---- fragment read bases (swizzled) ----
    const int s_rd = ((lane & 31) >> 1) & 3;
    const int c0s = ((lane >> 5) * 2) ^ s_rd;
    const unsigned char* aR0 = sm + (wr * 64 + (lane & 31)) * 64 + c0s * 16;
    const unsigned char* aR1 = sm + (wr * 64 + (lane & 31)) * 64 + (c0s ^ 1) * 16;
    const unsigned char* bR0 = sm + 8192 + (wc * 64 + (lane & 31)) * 64 + c0s * 16;
    const unsigned char* bR1 = sm + 8192 + (wc * 64 + (lane & 31)) * 64 + (c0s ^ 1) * 16;

    f32x16 acc[4] = {};   // [i 0..1][j 0..1] -> acc[i*2+j]

#define COMPUTE(qo)                                                       \
    do {                                                                  \
        i32x8 fb0 = cat8(*(const i32x4*)(bR0 + (qo)),                     \
                         *(const i32x4*)(bR1 + (qo)));                    \
        i32x8 fb1 = cat8(*(const i32x4*)(bR0 + (qo) + 2048),              \
                         *(const i32x4*)(bR1 + (qo) + 2048));             \
        i32x8 fa0 = cat8(*(const i32x4*)(aR0 + (qo)),                     \
                         *(const i32x4*)(aR1 + (qo)));                    \
        i32x8 fa1 = cat8(*(const i32x4*)(aR0 + (qo) + 2048),              \
                         *(const i32x4*)(aR1 + (qo) + 2048));             \
        __builtin_amdgcn_s_setprio(1);                                    \
        acc[0] = MXMFMA(fa0, fb0, acc[0]);                                \
        acc[1] = MXMFMA(fa0, fb1, acc[1]);                                \
        acc[2] = MXMFMA(fa1, fb0, acc[2]);                                \
        acc[3] = MXMFMA(fa1, fb1, acc[3]);                                \
        __builtin_amdgcn_s_setprio(0);                                    \
    } while (0)

    // ---- prologue: tiles 0,1 staged into bufs 0,1 (8 loads in flight) ----
    STAGE(0, 0);
    STAGE(1, 1);

    // main loop: stages t+2; WAITV(4) retires tile t, keeps t+1 flying
    #pragma unroll 4
    for (int t = 0; t < NIT - 2; ++t) {
        WAITV(4);
        BAR();
        STAGE((t + 2) & 3, t + 2);   // buf (t-2)&3: reads done at t-2
        COMPUTE((t & 3) * 16384);
    }
    // peeled tail (no staging)
    WAITV(4); BAR(); COMPUTE(((NIT - 2) & 3) * 16384);
    WAITV(0); BAR(); COMPUTE(((NIT - 1) & 3) * 16384);

    // ---- fused epilogue ----
    // 32x32 C/D layout: col = lane&31, row = (reg&3)+8*(reg>>2)+4*(lane>>5).
    const float c1m = 2.0f * INV_SS / (float)DDIM;
    const float c2 = 1.0f / (float)DDIM;
    const int gn0 = bn + wc * 64 + (lane & 31);
    const int gm_b = bm + wr * 64 + (lane >> 5) * 4;
    const float wv0 = wsq[gn0];
    const float wv1 = wsq[gn0 + 32];
    #pragma unroll
    for (int i = 0; i < 2; ++i)
        #pragma unroll
        for (int g = 0; g < 4; ++g)
            #pragma unroll
            for (int r = 0; r < 4; ++r) {
                const int gm = gm_b + i * 32 + g * 8 + r;
                const float xs = xsq[gm];
                out[(size_t)gm * CDIM + gn0] =
                    acc[i * 2 + 0][g * 4 + r] * c1m - (xs + wv0) * c2;
                out[(size_t)gm * CDIM + gn0 + 32] =
                    acc[i * 2 + 1][g * 4 + r] * c1m - (xs + wv1) * c2;
            }
#undef STAGE
#undef COMPUTE
}

// --- Fallback: naive fp32 (any ws) ---
__global__ void fallback_kernel(const float* __restrict__ x, const float* __restrict__ W,
                                float* __restrict__ out)
{
    int c = blockIdx.x * blockDim.x + threadIdx.x;
    int b = blockIdx.y;
    if (c >= CDIM) return;
    const float* xr = x + (size_t)b * DDIM;
    const float* wr = W + (size_t)c * DDIM;
    float xs = 0.f, ws = 0.f, cr = 0.f;
    for (int d = 0; d < DDIM; ++d) {
        float xv = xr[d], wv = wr[d];
        xs += xv * xv; ws += wv * wv; cr += xv * wv;
    }
    out[(size_t)b * CDIM + c] = (2.0f * cr - xs - ws) / (float)DDIM;
}

extern "C" void kernel_launch(void* const* d_in, const int* in_sizes, int n_in,
                              void* d_out, int out_size, void* d_ws, size_t ws_size,
                              hipStream_t stream) {
    const float* x = (const float*)d_in[0];   // [B, D] fp32
    const float* W = (const float*)d_in[1];   // [C, D] fp32
    float* out = (float*)d_out;               // [B, C] fp32

    size_t need = (size_t)(BDIM + CDIM) * DDIM                 // fp8 inputs 20 MB
                + (size_t)(BDIM + CDIM) * sizeof(float);       // norms
    if (ws_size < need) {
        fallback_kernel<<<dim3(CDIM / 256, BDIM), 256, 0, stream>>>(x, W, out);
        return;
    }

    unsigned char* xb = (unsigned char*)d_ws;              // 16 MB
    unsigned char* wb = xb + (size_t)BDIM * DDIM;          // 4 MB
    float* xsq = (float*)(wb + (size_t)CDIM * DDIM);       // 16 KB
    float* wsq = xsq + BDIM;                               // 4 KB

    cvt_rowsq<<<(BDIM + CDIM) / 4, 256, 0, stream>>>(x, W, xb, wb, xsq, wsq);
    gemm_eucl<<<dim3(BDIM / TM, CDIM / TN), 256, 0, stream>>>(xb, wb, xsq, wsq, out);
}